// Round 4
// baseline (2714.326 us; speedup 1.0000x reference)
//
#include <hip/hip_runtime.h>
#include <hip/hip_fp16.h>

#define TLEN 16000

typedef _Float16 h16;
typedef __attribute__((ext_vector_type(8))) _Float16 half8;
typedef __attribute__((ext_vector_type(4))) _Float16 half4;
typedef __attribute__((ext_vector_type(4))) float f32x4;

// async global->LDS, 16B/lane; LDS base wave-uniform (lane*16 auto-offset)
__device__ __forceinline__ void gload16(const void* g, void* l) {
  __builtin_amdgcn_global_load_lds((const __attribute__((address_space(1))) void*)g,
                                   (__attribute__((address_space(3))) void*)l, 16, 0, 0);
}

// tanh(g)*sigmoid(g), stable for g << 0
__device__ __forceinline__ float gated_act(float g) {
  float gc = fmaxf(g, -30.0f);
  float e1 = __expf(-gc);
  float e2 = e1 * e1;
  return (1.0f - e2) / ((1.0f + e2) * (1.0f + e1));
}

// ---------------- prep: weight repack f32->f16 + x16p pad zero ----------------
// w2h  [l][o<256][k=512] (k<256: tap0/shifted, else tap1)
// resh [l][o][i] 15 layers; skiph [s][l*256+c] (K=4096 layer-major cols)
// couth[o][s], cendh[p][o], sbias[s]=sum_l skip_b[l][s]
__global__ __launch_bounds__(256) void prep_k(
    const float* __restrict__ dw, const float* __restrict__ rw,
    const float* __restrict__ sw, const float* __restrict__ cow,
    const float* __restrict__ cew, const float* __restrict__ sb,
    h16* __restrict__ w2h, h16* __restrict__ resh, h16* __restrict__ skiph,
    h16* __restrict__ couth, h16* __restrict__ cendh, float* __restrict__ sbias,
    h16* __restrict__ x16p)
{
  size_t u = (size_t)blockIdx.x * 256 + threadIdx.x;
  if (u < 2097152) {
    int l = (int)(u >> 17);
    int rem = (int)(u & 131071);
    int o = rem >> 9, k = rem & 511;
    float v = (k < 256) ? dw[(((size_t)l * 512 + o) * 256 + k) * 2]
                        : dw[(((size_t)l * 512 + o) * 256 + (k - 256)) * 2 + 1];
    w2h[u] = (h16)v;
    return;
  }
  u -= 2097152;
  if (u < 983040) { resh[u] = (h16)rw[u]; return; }
  u -= 983040;
  if (u < 2097152) {  // skiph[s][l*256+c]
    int s = (int)(u >> 12);
    int r = (int)(u & 4095);
    int l = r >> 8, c = r & 255;
    skiph[u] = (h16)sw[((size_t)l * 512 + s) * 256 + c];
    return;
  }
  u -= 2097152;
  if (u < 131072) { couth[u] = (h16)cow[u]; return; }
  u -= 131072;
  if (u < 65536) { cendh[u] = (h16)cew[u]; return; }
  u -= 65536;
  if (u < 512) {
    float s = 0.f;
    for (int l = 0; l < 16; l++) s += sb[(size_t)l * 512 + u];
    sbias[u] = s;
    return;
  }
  u -= 512;
  if (u < 65536) x16p[u] = (h16)0.f;  // zero rows [0,256) pad
}

// ---------------- embedding: xf32[t][c] and x16p[t+256][c] ----------------
__global__ __launch_bounds__(256) void embed_k(
    const int* __restrict__ tok, const float* __restrict__ emb,
    float* __restrict__ x, h16* __restrict__ x16p)
{
  const size_t i = (size_t)blockIdx.x * 256 + threadIdx.x;  // 4 floats / thread
  const int t = (int)(i >> 6);
  const int c4 = (int)(i & 63) * 4;
  const int tk = tok[t];
  f32x4 v = *(const f32x4*)(emb + (size_t)tk * 256 + c4);
  *(f32x4*)(x + (size_t)t * 256 + c4) = v;
  half4 hv;
#pragma unroll
  for (int j = 0; j < 4; j++) hv[j] = (h16)v[j];
  *(half4*)(x16p + (size_t)(t + 256) * 256 + c4) = hv;
}

// ---------------- 2-phase dbuf MFMA GEMM: D[t][n] = sum_k A[t][k]*W[n][k] ------------
// BM=64, BK=32, 256 thr = 4 waves. BN=128: 2x2 waves, wave tile 32x64, acc[2][4].
//                                  BN=256: 1x4 waves, wave tile 64x64, acc[4][4].
// Linear LDS [rows][32] via global_load_lds w16; double-buffered, one barrier/K-step.
// All epilogue global I/O coalesced (16B/lane) via per-wave LDS transpose.
// MODE 0: dilate  A=x16p (256-row pad; k<256 reads shifted tap) -> act slot: gated(D+dil_b)
// MODE 1: res     A=act slot; xf32 += D+resb (coalesced f32 RMW); x16p=(h16)xf32
// MODE 2: skip1   A=act (K=2048, layers 0-7) -> sp f32 write
// MODE 3: skip2   A=act (layers 8-15) -> sk16 = (h16)relu(D + sp + sbias)
// MODE 4: h1      A=sk16 stride 512 -> h116 = (h16)relu(D)
template<int KTOT, int AST, int WST, int BN, int MODE>
__global__ __launch_bounds__(256) void gemm4_k(
    const h16* __restrict__ A, const h16* __restrict__ W,
    const float* __restrict__ bias, h16* __restrict__ o16,
    float* __restrict__ of32, const float* __restrict__ sp_in)
{
  constexpr int NT = KTOT / 32;
  constexpr int MI = (BN == 128) ? 2 : 4;
  constexpr int OST = (MODE == 0) ? 2048 : (MODE == 3) ? 512 : 256;
  __shared__ h16 As[2][64 * 32];
  __shared__ h16 Bs[2][BN * 32];
  __shared__ __align__(16) char tscr[17408];  // union: h16 [4][16][72] | f32 [4][16][68]
  h16 (*tbufH)[16][72] = (h16(*)[16][72])tscr;
  float (*tbufF)[16][68] = (float(*)[16][68])tscr;

  const int tid  = threadIdx.x;
  const int lane = tid & 63;
  const int w    = tid >> 6;
  const int r16  = lane & 15;
  const int kg   = lane >> 4;
  const int t0   = blockIdx.x * 64;
  const int n0w  = blockIdx.y * BN;
  const int wm   = (BN == 128) ? (w >> 1) : 0;
  const int wn   = (BN == 128) ? (w & 1) : w;
  const int arow_base = wm * 32;
  const int brow_base = wn * 64;
  const int srow  = lane >> 2;
  const int sunit = (lane & 3) * 8;

  auto stage = [&](int bi, int kk) {
    const int k0 = kk * 32;
    {
      const h16* src;
      if constexpr (MODE == 0)
        src = A + (size_t)(t0 + w * 16 + srow + (k0 < 256 ? 0 : 256)) * AST + (k0 & 255) + sunit;
      else
        src = A + (size_t)(t0 + w * 16 + srow) * AST + k0 + sunit;
      gload16(src, &As[bi][(w * 16) * 32]);
    }
#pragma unroll
    for (int q = 0; q < BN / 64; q++) {
      const int row = w * (BN / 4) + q * 16;
      const h16* src = W + (size_t)(n0w + row + srow) * WST + k0 + sunit;
      gload16(src, &Bs[bi][row * 32]);
    }
  };

  f32x4 acc[MI][4];
#pragma unroll
  for (int i = 0; i < MI; i++)
#pragma unroll
    for (int j = 0; j < 4; j++) acc[i][j] = (f32x4){0.f, 0.f, 0.f, 0.f};

  stage(0, 0);
  __syncthreads();

  for (int t = 0; t < NT; t++) {
    const int cur = t & 1;
    if (t + 1 < NT) stage(cur ^ 1, t + 1);  // prefetch overlaps ds_read+MFMA
    half8 af[MI], bf[4];
#pragma unroll
    for (int mi = 0; mi < MI; mi++)
      af[mi] = *(const half8*)&As[cur][(arow_base + mi * 16 + r16) * 32 + kg * 8];
#pragma unroll
    for (int ni = 0; ni < 4; ni++)
      bf[ni] = *(const half8*)&Bs[cur][(brow_base + ni * 16 + r16) * 32 + kg * 8];
#pragma unroll
    for (int mi = 0; mi < MI; mi++)
#pragma unroll
      for (int ni = 0; ni < 4; ni++)
        acc[mi][ni] = __builtin_amdgcn_mfma_f32_16x16x32_f16(af[mi], bf[ni], acc[mi][ni], 0, 0, 0);
    __syncthreads();
  }

  const int rr = lane >> 2;
  const int cc = (lane & 3) * 16;
  const int colw = n0w + brow_base;  // wave's global col base

#pragma unroll
  for (int mi = 0; mi < MI; mi++) {
    const int trow = t0 + arow_base + mi * 16;
    if constexpr (MODE == 1 || MODE == 2 || MODE == 3) {
      // ---- f32 transpose path
#pragma unroll
      for (int ni = 0; ni < 4; ni++)
#pragma unroll
        for (int g = 0; g < 4; g++) {
          float v = acc[mi][ni][g];
          if constexpr (MODE == 1) v += bias[colw + ni * 16 + r16];
          tbufF[w][kg * 4 + g][ni * 16 + r16] = v;
        }
      if constexpr (MODE == 1) {  // res: coalesced xf32 RMW + x16p h16 write
        float* xrow = of32 + (size_t)(trow + rr) * 256 + colw + cc;
        h16* xprow = o16 + (size_t)(trow + rr + 256) * 256 + colw + cc;
        half8 hv0, hv1;
#pragma unroll
        for (int j = 0; j < 4; j++) {
          f32x4 v = *(const f32x4*)(xrow + j * 4);
          f32x4 d = *(const f32x4*)&tbufF[w][rr][cc + j * 4];
          v += d;
          *(f32x4*)(xrow + j * 4) = v;
#pragma unroll
          for (int e = 0; e < 4; e++) {
            if (j < 2) hv0[j * 4 + e] = (h16)v[e];
            else       hv1[(j - 2) * 4 + e] = (h16)v[e];
          }
        }
        *(half8*)xprow       = hv0;
        *(half8*)(xprow + 8) = hv1;
      } else if constexpr (MODE == 2) {  // skip half1: sp f32 write
        float* dst = of32 + (size_t)(trow + rr) * 512 + colw + cc;
#pragma unroll
        for (int j = 0; j < 4; j++)
          *(f32x4*)(dst + j * 4) = *(const f32x4*)&tbufF[w][rr][cc + j * 4];
      } else {  // skip half2: + sp + sbias, relu -> sk16 h16
        const float* sprow = sp_in + (size_t)(trow + rr) * 512 + colw + cc;
        h16* dst = o16 + (size_t)(trow + rr) * 512 + colw + cc;
        half8 hv0, hv1;
#pragma unroll
        for (int j = 0; j < 4; j++) {
          f32x4 v = *(const f32x4*)&tbufF[w][rr][cc + j * 4];
          f32x4 s = *(const f32x4*)(sprow + j * 4);
          f32x4 sb = *(const f32x4*)(bias + colw + cc + j * 4);
          v = v + s + sb;
#pragma unroll
          for (int e = 0; e < 4; e++) {
            float r = fmaxf(v[e], 0.f);
            if (j < 2) hv0[j * 4 + e] = (h16)r;
            else       hv1[(j - 2) * 4 + e] = (h16)r;
          }
        }
        *(half8*)dst       = hv0;
        *(half8*)(dst + 8) = hv1;
      }
    } else {
      // ---- h16 transpose path (MODE 0 gated / MODE 4 relu)
#pragma unroll
      for (int ni = 0; ni < 4; ni++)
#pragma unroll
        for (int g = 0; g < 4; g++) {
          float v = acc[mi][ni][g];
          if constexpr (MODE == 0) v = gated_act(v + bias[colw + ni * 16 + r16]);
          else                     v = fmaxf(v, 0.f);
          tbufH[w][kg * 4 + g][ni * 16 + r16] = (h16)v;
        }
      h16* dst = o16 + (size_t)(trow + rr) * OST + colw + cc;
      *(half8*)dst       = *(const half8*)&tbufH[w][rr][cc];
      *(half8*)(dst + 8) = *(const half8*)&tbufH[w][rr][cc + 8];
    }
  }
}

// ---------------- head: logits = h1 @ cend^T (K=256,N=256) + softmax + (O,T) write ----
__global__ __launch_bounds__(256) void head_k(
    const h16* __restrict__ A, const h16* __restrict__ W, float* __restrict__ out)
{
  __shared__ h16 As[32][40];
  __shared__ h16 Bs[256][40];
  __shared__ float lg[32][257];

  const int tid = threadIdx.x;
  const int t0  = blockIdx.x * 32;
  const int lane = tid & 63, wid = tid >> 6;
  const int r16 = lane & 15, kg = lane >> 4;

  f32x4 acc[2][4];
#pragma unroll
  for (int i = 0; i < 2; i++)
#pragma unroll
    for (int j = 0; j < 4; j++) acc[i][j] = (f32x4){0.f, 0.f, 0.f, 0.f};

  const int arow = tid >> 3, asub = tid & 7;

  for (int k0 = 0; k0 < 256; k0 += 32) {
    {
      const h16* src = A + (size_t)(t0 + arow) * 256 + k0 + asub * 4;
      *(half4*)&As[arow][asub * 4] = *(const half4*)src;
    }
    {
      const h16* src = W + (size_t)tid * 256 + k0;
#pragma unroll
      for (int q = 0; q < 4; q++) *(half8*)&Bs[tid][q * 8] = *(const half8*)(src + q * 8);
    }
    __syncthreads();
    half8 af[2], bf[4];
#pragma unroll
    for (int mi = 0; mi < 2; mi++) af[mi] = *(const half8*)&As[mi * 16 + r16][kg * 8];
#pragma unroll
    for (int ni = 0; ni < 4; ni++) bf[ni] = *(const half8*)&Bs[wid * 64 + ni * 16 + r16][kg * 8];
#pragma unroll
    for (int mi = 0; mi < 2; mi++)
#pragma unroll
      for (int ni = 0; ni < 4; ni++)
        acc[mi][ni] = __builtin_amdgcn_mfma_f32_16x16x32_f16(af[mi], bf[ni], acc[mi][ni], 0, 0, 0);
    __syncthreads();
  }

#pragma unroll
  for (int mi = 0; mi < 2; mi++) {
    const int rl = mi * 16 + kg * 4;
#pragma unroll
    for (int ni = 0; ni < 4; ni++) {
      const int n = wid * 64 + ni * 16 + r16;
#pragma unroll
      for (int g = 0; g < 4; g++) lg[rl + g][n] = acc[mi][ni][g];
    }
  }
  __syncthreads();

  for (int i = 0; i < 8; i++) {
    const int r = wid * 8 + i;
    float v[4];
#pragma unroll
    for (int j = 0; j < 4; j++) v[j] = lg[r][lane + 64 * j];
    float m = fmaxf(fmaxf(v[0], v[1]), fmaxf(v[2], v[3]));
#pragma unroll
    for (int off = 32; off >= 1; off >>= 1) m = fmaxf(m, __shfl_xor(m, off));
    float s = 0.f;
#pragma unroll
    for (int j = 0; j < 4; j++) { v[j] = __expf(v[j] - m); s += v[j]; }
#pragma unroll
    for (int off = 32; off >= 1; off >>= 1) s += __shfl_xor(s, off);
    const float inv = 1.f / s;
#pragma unroll
    for (int j = 0; j < 4; j++) lg[r][lane + 64 * j] = v[j] * inv;
  }
  __syncthreads();

  const int tl = tid & 31, og = tid >> 5;
  for (int j = 0; j < 32; j++) {
    const int o = og * 32 + j;
    out[(size_t)o * TLEN + t0 + tl] = lg[tl][o];
  }
}

extern "C" void kernel_launch(void* const* d_in, const int* in_sizes, int n_in,
                              void* d_out, int out_size, void* d_ws, size_t ws_size,
                              hipStream_t stream)
{
  const int*   tokens = (const int*)  d_in[0];
  const float* embedw = (const float*)d_in[1];
  const float* dil_w  = (const float*)d_in[2];
  const float* dil_b  = (const float*)d_in[3];
  const float* resw   = (const float*)d_in[4];
  const float* resb   = (const float*)d_in[5];
  const float* skipw  = (const float*)d_in[6];
  const float* skipb  = (const float*)d_in[7];
  const float* coutw  = (const float*)d_in[8];
  const float* cendw  = (const float*)d_in[9];
  float* out = (float*)d_out;

  // ws budget: 133.8 MB (proven-good ceiling >= 158.2 MB from round 1)
  char* p = (char*)d_ws;
  auto carve = [&](size_t bytes) { char* r = p; p += (bytes + 255) & ~(size_t)255; return r; };
  h16* w2h      = (h16*)carve((size_t)16 * 256 * 512 * 2);       //  4.19 MB
  h16* resh     = (h16*)carve((size_t)15 * 256 * 256 * 2);       //  1.97 MB
  h16* skiph    = (h16*)carve((size_t)512 * 4096 * 2);           //  4.19 MB
  h16* couth    = (h16*)carve((size_t)256 * 512 * 2);            //  0.26 MB
  h16* cendh    = (h16*)carve((size_t)256 * 256 * 2);            //  0.13 MB
  float* sbias  = (float*)carve(512 * 4);
  float* xf32   = (float*)carve((size_t)TLEN * 256 * 4);         // 16.38 MB
  h16*  x16p    = (h16*) carve((size_t)(TLEN + 256) * 256 * 2);  //  8.32 MB
  h16*  act     = (h16*) carve((size_t)TLEN * 2048 * 2);         // 65.54 MB [t][l&7][c]
  float* sp     = (float*)carve((size_t)TLEN * 512 * 4);         // 32.77 MB
  h16* sk16 = (h16*)xf32;  // xf32 dead after res_14
  h16* h116 = act;         // act dead after skip half2

  prep_k<<<dim3(21250), 256, 0, stream>>>(
      dil_w, resw, skipw, coutw, cendw, skipb,
      w2h, resh, skiph, couth, cendh, sbias, x16p);

  for (int b = 0; b < 4; b++) {
    embed_k<<<dim3(4000), 256, 0, stream>>>(tokens + (size_t)b * TLEN, embedw, xf32, x16p);

    for (int l = 0; l < 16; l++) {
      gemm4_k<512, 256, 512, 128, 0><<<dim3(250, 2), 256, 0, stream>>>(
          x16p, w2h + (size_t)l * 131072, dil_b + (size_t)l * 512,
          act + (l & 7) * 256, nullptr, nullptr);
      if (l < 15)
        gemm4_k<256, 2048, 256, 128, 1><<<dim3(250, 2), 256, 0, stream>>>(
            act + (l & 7) * 256, resh + (size_t)l * 65536, resb + (size_t)l * 256,
            x16p, xf32, nullptr);
      if (l == 7)  // layers 0-7 complete, before dilate_8 overwrites slot 0
        gemm4_k<2048, 2048, 4096, 256, 2><<<dim3(250, 2), 256, 0, stream>>>(
            act, skiph, nullptr, nullptr, sp, nullptr);
    }

    gemm4_k<2048, 2048, 4096, 256, 3><<<dim3(250, 2), 256, 0, stream>>>(
        act, skiph + 2048, sbias, sk16, nullptr, sp);
    gemm4_k<512, 512, 512, 128, 4><<<dim3(250, 2), 256, 0, stream>>>(
        sk16, couth, nullptr, h116, nullptr, nullptr);
    head_k<<<dim3(500), 256, 0, stream>>>(h116, cendh, out + (size_t)b * 256 * TLEN);
  }
}

// Round 5
// 2281.124 us; speedup vs baseline: 1.1899x; 1.1899x over previous
//
#include <hip/hip_runtime.h>
#include <hip/hip_fp16.h>

#define TLEN 16000
#define BC 2  // batches per dispatch (blockIdx.z)

typedef _Float16 h16;
typedef __attribute__((ext_vector_type(8))) _Float16 half8;
typedef __attribute__((ext_vector_type(4))) _Float16 half4;
typedef __attribute__((ext_vector_type(4))) float f32x4;

// async global->LDS, 16B/lane; LDS base wave-uniform (lane*16 auto-offset)
__device__ __forceinline__ void gload16(const void* g, void* l) {
  __builtin_amdgcn_global_load_lds((const __attribute__((address_space(1))) void*)g,
                                   (__attribute__((address_space(3))) void*)l, 16, 0, 0);
}

// tanh(g)*sigmoid(g), stable for g << 0
__device__ __forceinline__ float gated_act(float g) {
  float gc = fmaxf(g, -30.0f);
  float e1 = __expf(-gc);
  float e2 = e1 * e1;
  return (1.0f - e2) / ((1.0f + e2) * (1.0f + e1));
}

// ---------------- prep: weight repack f32->f16 ----------------
// w2h  [l][o<256][k=512] (k<256: tap0/shifted, else tap1)
// resh [l][o][i] 15 layers
// skiph[ch][s][lc*256+c] 4 chunks of 4 layers (K=1024 per chunk)
// couth[o][s], cendh[p][o], sbias[s]=sum_l skip_b[l][s]
__global__ __launch_bounds__(256) void prep_k(
    const float* __restrict__ dw, const float* __restrict__ rw,
    const float* __restrict__ sw, const float* __restrict__ cow,
    const float* __restrict__ cew, const float* __restrict__ sb,
    h16* __restrict__ w2h, h16* __restrict__ resh, h16* __restrict__ skiph,
    h16* __restrict__ couth, h16* __restrict__ cendh, float* __restrict__ sbias)
{
  size_t u = (size_t)blockIdx.x * 256 + threadIdx.x;
  if (u < 2097152) {
    int l = (int)(u >> 17);
    int rem = (int)(u & 131071);
    int o = rem >> 9, k = rem & 511;
    float v = (k < 256) ? dw[(((size_t)l * 512 + o) * 256 + k) * 2]
                        : dw[(((size_t)l * 512 + o) * 256 + (k - 256)) * 2 + 1];
    w2h[u] = (h16)v;
    return;
  }
  u -= 2097152;
  if (u < 983040) { resh[u] = (h16)rw[u]; return; }
  u -= 983040;
  if (u < 2097152) {  // skiph[ch][s][lc*256+c]
    int ch = (int)(u >> 19);
    int r  = (int)(u & 524287);
    int s  = r >> 10;
    int q  = r & 1023;
    int l  = ch * 4 + (q >> 8), c = q & 255;
    skiph[u] = (h16)sw[((size_t)l * 512 + s) * 256 + c];
    return;
  }
  u -= 2097152;
  if (u < 131072) { couth[u] = (h16)cow[u]; return; }
  u -= 131072;
  if (u < 65536) { cendh[u] = (h16)cew[u]; return; }
  u -= 65536;
  if (u < 512) {
    float s = 0.f;
    for (int l = 0; l < 16; l++) s += sb[(size_t)l * 512 + u];
    sbias[u] = s;
  }
}

// ---------------- embedding: xf32[b][t][c] ----------------
__global__ __launch_bounds__(256) void embed_k(
    const int* __restrict__ tok, const float* __restrict__ emb, float* __restrict__ x)
{
  const int b = blockIdx.y;
  const size_t i = (size_t)blockIdx.x * 256 + threadIdx.x;  // 4 floats / thread
  const int t = (int)(i >> 6);
  const int c4 = (int)(i & 63) * 4;
  const int tk = tok[(size_t)b * TLEN + t];
  *(f32x4*)(x + ((size_t)b * TLEN + t) * 256 + c4) = *(const f32x4*)(emb + (size_t)tk * 256 + c4);
}

// ---------------- slim 2-phase dbuf MFMA GEMM: D[t][n] = sum_k A[t][k]*W[n][k] --------
// BM=64, BN=128, BK=32; 256 thr = 4 waves 2x2, wave tile 32x64, acc[2][4].
// LDS 24KB total (dbuf A 8KB + dbuf B 16KB); epilogue transpose aliases the same LDS.
// __launch_bounds__(256,4): target 4 blocks/CU = 16 waves/CU for latency hiding.
// MODE 0: dilate  A=xf32 f32 reg-staged w/ convert (tap0 k<256 reads row t-256, zero t<256)
//                 -> act slot [t][1024 interleave], gated(D + dil_b)
// MODE 1: res     A=act slot (AST=1024), K=256 -> coalesced xf32 f32 RMW (+resb)
// MODE 2: skip chunk 0: A=act K=1024 -> sp h16 = (h16)(D + sbias)
// MODE 3: skip chunk 1,2: sp h16 += D   (RMW)
// MODE 4: skip chunk 3: sk16 = (h16)relu(sp + D)
// MODE 5: h1      A=sk16 (AST=512), K=512 -> h116 = relu h16
template<int KTOT, int AST, int WST, int MODE>
__global__ __launch_bounds__(256, 4) void gemm5_k(
    const void* __restrict__ A, const h16* __restrict__ W,
    const float* __restrict__ bias, h16* __restrict__ o16,
    float* __restrict__ of32, const h16* __restrict__ spin)
{
  constexpr int NT = KTOT / 32;
  __shared__ __align__(16) char smem[24576];
  h16* As = (h16*)smem;          // [2][64*32]
  h16* Bs = (h16*)smem + 4096;   // [2][128*32]

  const int tid  = threadIdx.x;
  const int lane = tid & 63;
  const int w    = tid >> 6;
  const int r16  = lane & 15;
  const int kg   = lane >> 4;
  const int wm   = w >> 1;
  const int wn   = w & 1;
  const int t0   = blockIdx.x * 64;
  const int n0w  = blockIdx.y * 128;
  const int bz   = blockIdx.z;
  const int srow = lane >> 2;
  const int sc8  = (lane & 3) * 8;

  const float* Af = (const float*)A + (size_t)bz * TLEN * 256;        // MODE 0
  const h16*   Ah = (const h16*)A + (size_t)bz * TLEN * (size_t)AST;  // MODE >= 1

  auto stageB = [&](int bi, int k0) {
#pragma unroll
    for (int q = 0; q < 2; q++) {
      const h16* src = W + (size_t)(n0w + w * 32 + q * 16 + srow) * WST + k0 + sc8;
      gload16(src, Bs + bi * 4096 + (w * 32 + q * 16) * 32);
    }
  };
  auto stageA = [&](int bi, int k0) {  // MODE >= 1
    const h16* src = Ah + (size_t)(t0 + w * 16 + srow) * AST + k0 + sc8;
    gload16(src, As + bi * 2048 + (w * 16) * 32);
  };
  auto loadA0 = [&](int k0) -> half8 {  // MODE 0: f32 -> h16 reg-stage, dilated taps
    half8 av;
#pragma unroll
    for (int j = 0; j < 8; j++) av[j] = (h16)0.f;
    const bool tap0 = (k0 < 256);
    if (!(tap0 && t0 < 256)) {  // uniform: whole tile's tap0 rows < 0 iff t0 < 256
      const int srcrow = t0 + w * 16 + srow - (tap0 ? 256 : 0);
      const float* s = Af + (size_t)srcrow * 256 + (k0 & 255) + sc8;
      f32x4 v0 = *(const f32x4*)s;
      f32x4 v1 = *(const f32x4*)(s + 4);
#pragma unroll
      for (int j = 0; j < 4; j++) { av[j] = (h16)v0[j]; av[j + 4] = (h16)v1[j]; }
    }
    return av;
  };

  f32x4 acc[2][4];
#pragma unroll
  for (int i = 0; i < 2; i++)
#pragma unroll
    for (int j = 0; j < 4; j++) acc[i][j] = (f32x4){0.f, 0.f, 0.f, 0.f};

  half8 areg;
  if constexpr (MODE == 0) areg = loadA0(0);
  stageB(0, 0);
  if constexpr (MODE != 0) stageA(0, 0);
  else *(half8*)(As + (w * 16 + srow) * 32 + sc8) = areg;
  __syncthreads();

  for (int t = 0; t < NT; t++) {
    const int cur = t & 1;
    if (t + 1 < NT) {  // issue next-tile loads before compute (T14 issue-early)
      if constexpr (MODE == 0) areg = loadA0((t + 1) * 32);
      stageB(cur ^ 1, (t + 1) * 32);
      if constexpr (MODE != 0) stageA(cur ^ 1, (t + 1) * 32);
    }
    half8 af[2], bf[4];
#pragma unroll
    for (int mi = 0; mi < 2; mi++)
      af[mi] = *(const half8*)&As[cur * 2048 + (wm * 32 + mi * 16 + r16) * 32 + kg * 8];
#pragma unroll
    for (int ni = 0; ni < 4; ni++)
      bf[ni] = *(const half8*)&Bs[cur * 4096 + (wn * 64 + ni * 16 + r16) * 32 + kg * 8];
#pragma unroll
    for (int mi = 0; mi < 2; mi++)
#pragma unroll
      for (int ni = 0; ni < 4; ni++)
        acc[mi][ni] = __builtin_amdgcn_mfma_f32_16x16x32_f16(af[mi], bf[ni], acc[mi][ni], 0, 0, 0);
    if (t + 1 < NT)
      if constexpr (MODE == 0)  // write-late: reg->LDS after MFMA gave loads time
        *(half8*)(As + (cur ^ 1) * 2048 + (w * 16 + srow) * 32 + sc8) = areg;
    __syncthreads();
  }

  // ---- epilogue: per-wave transpose in ALIASED LDS (main-loop buffers are dead)
  h16*   tb = (h16*)(smem + w * 4352);   // [16][72] h16
  float* tf = (float*)(smem + w * 4352); // [16][68] f32
  const int rr = lane >> 2;
  const int cc = (lane & 3) * 16;
  const int colw = n0w + wn * 64;

#pragma unroll
  for (int mi = 0; mi < 2; mi++) {
    const int trow = t0 + wm * 32 + mi * 16;
    if constexpr (MODE == 0 || MODE == 5) {
#pragma unroll
      for (int ni = 0; ni < 4; ni++)
#pragma unroll
        for (int g = 0; g < 4; g++) {
          float v = acc[mi][ni][g];
          if constexpr (MODE == 0) v = gated_act(v + bias[colw + ni * 16 + r16]);
          else                     v = fmaxf(v, 0.f);
          tb[(kg * 4 + g) * 72 + ni * 16 + r16] = (h16)v;
        }
      constexpr int OST = (MODE == 0) ? 1024 : 256;
      h16* dst = o16 + (size_t)bz * TLEN * OST + (size_t)(trow + rr) * OST + colw + cc;
      *(half8*)dst       = *(const half8*)&tb[rr * 72 + cc];
      *(half8*)(dst + 8) = *(const half8*)&tb[rr * 72 + cc + 8];
    } else {
#pragma unroll
      for (int ni = 0; ni < 4; ni++)
#pragma unroll
        for (int g = 0; g < 4; g++) {
          float v = acc[mi][ni][g];
          if constexpr (MODE == 1 || MODE == 2) v += bias[colw + ni * 16 + r16];
          tf[(kg * 4 + g) * 68 + ni * 16 + r16] = v;
        }
      if constexpr (MODE == 1) {  // coalesced f32 residual RMW
        float* xrow = of32 + (size_t)bz * TLEN * 256 + (size_t)(trow + rr) * 256 + colw + cc;
#pragma unroll
        for (int j = 0; j < 4; j++) {
          f32x4 v = *(const f32x4*)(xrow + j * 4);
          v += *(const f32x4*)(tf + rr * 68 + cc + j * 4);
          *(f32x4*)(xrow + j * 4) = v;
        }
      } else {  // skip chunk paths (sp h16 accumulate / finalize)
        half8 o0, o1;
        if constexpr (MODE == 2) {
#pragma unroll
          for (int e = 0; e < 8; e++) {
            o0[e] = (h16)tf[rr * 68 + cc + e];
            o1[e] = (h16)tf[rr * 68 + cc + 8 + e];
          }
        } else {
          const h16* sps = spin + (size_t)bz * TLEN * 512 + (size_t)(trow + rr) * 512 + colw + cc;
          half8 s0 = *(const half8*)sps;
          half8 s1 = *(const half8*)(sps + 8);
#pragma unroll
          for (int e = 0; e < 8; e++) {
            float v0 = tf[rr * 68 + cc + e] + (float)s0[e];
            float v1 = tf[rr * 68 + cc + 8 + e] + (float)s1[e];
            if constexpr (MODE == 4) { v0 = fmaxf(v0, 0.f); v1 = fmaxf(v1, 0.f); }
            o0[e] = (h16)v0; o1[e] = (h16)v1;
          }
        }
        h16* dst = o16 + (size_t)bz * TLEN * 512 + (size_t)(trow + rr) * 512 + colw + cc;
        *(half8*)dst       = o0;
        *(half8*)(dst + 8) = o1;
      }
    }
  }
}

// ---------------- head: logits = h1 @ cend^T (K=256,N=256) + softmax + (O,T) write ----
__global__ __launch_bounds__(256) void head_k(
    const h16* __restrict__ A, const h16* __restrict__ W, float* __restrict__ out)
{
  __shared__ h16 As[32][40];
  __shared__ h16 Bs[256][40];
  __shared__ float lg[32][257];

  const int tid = threadIdx.x;
  const int bz  = blockIdx.z;
  const int t0  = blockIdx.x * 32;
  const int lane = tid & 63, wid = tid >> 6;
  const int r16 = lane & 15, kg = lane >> 4;
  const h16* Ab = A + (size_t)bz * TLEN * 256;

  f32x4 acc[2][4];
#pragma unroll
  for (int i = 0; i < 2; i++)
#pragma unroll
    for (int j = 0; j < 4; j++) acc[i][j] = (f32x4){0.f, 0.f, 0.f, 0.f};

  const int arow = tid >> 3, asub = tid & 7;

  for (int k0 = 0; k0 < 256; k0 += 32) {
    {
      const h16* src = Ab + (size_t)(t0 + arow) * 256 + k0 + asub * 4;
      *(half4*)&As[arow][asub * 4] = *(const half4*)src;
    }
    {
      const h16* src = W + (size_t)tid * 256 + k0;
#pragma unroll
      for (int q = 0; q < 4; q++) *(half8*)&Bs[tid][q * 8] = *(const half8*)(src + q * 8);
    }
    __syncthreads();
    half8 af[2], bf[4];
#pragma unroll
    for (int mi = 0; mi < 2; mi++) af[mi] = *(const half8*)&As[mi * 16 + r16][kg * 8];
#pragma unroll
    for (int ni = 0; ni < 4; ni++) bf[ni] = *(const half8*)&Bs[wid * 64 + ni * 16 + r16][kg * 8];
#pragma unroll
    for (int mi = 0; mi < 2; mi++)
#pragma unroll
      for (int ni = 0; ni < 4; ni++)
        acc[mi][ni] = __builtin_amdgcn_mfma_f32_16x16x32_f16(af[mi], bf[ni], acc[mi][ni], 0, 0, 0);
    __syncthreads();
  }

#pragma unroll
  for (int mi = 0; mi < 2; mi++) {
    const int rl = mi * 16 + kg * 4;
#pragma unroll
    for (int ni = 0; ni < 4; ni++) {
      const int n = wid * 64 + ni * 16 + r16;
#pragma unroll
      for (int g = 0; g < 4; g++) lg[rl + g][n] = acc[mi][ni][g];
    }
  }
  __syncthreads();

  for (int i = 0; i < 8; i++) {
    const int r = wid * 8 + i;
    float v[4];
#pragma unroll
    for (int j = 0; j < 4; j++) v[j] = lg[r][lane + 64 * j];
    float m = fmaxf(fmaxf(v[0], v[1]), fmaxf(v[2], v[3]));
#pragma unroll
    for (int off = 32; off >= 1; off >>= 1) m = fmaxf(m, __shfl_xor(m, off));
    float s = 0.f;
#pragma unroll
    for (int j = 0; j < 4; j++) { v[j] = __expf(v[j] - m); s += v[j]; }
#pragma unroll
    for (int off = 32; off >= 1; off >>= 1) s += __shfl_xor(s, off);
    const float inv = 1.f / s;
#pragma unroll
    for (int j = 0; j < 4; j++) lg[r][lane + 64 * j] = v[j] * inv;
  }
  __syncthreads();

  const int tl = tid & 31, og = tid >> 5;
  for (int j = 0; j < 32; j++) {
    const int o = og * 32 + j;
    out[((size_t)bz * 256 + o) * TLEN + t0 + tl] = lg[tl][o];
  }
}

extern "C" void kernel_launch(void* const* d_in, const int* in_sizes, int n_in,
                              void* d_out, int out_size, void* d_ws, size_t ws_size,
                              hipStream_t stream)
{
  const int*   tokens = (const int*)  d_in[0];
  const float* embedw = (const float*)d_in[1];
  const float* dil_w  = (const float*)d_in[2];
  const float* dil_b  = (const float*)d_in[3];
  const float* resw   = (const float*)d_in[4];
  const float* resb   = (const float*)d_in[5];
  const float* skipw  = (const float*)d_in[6];
  const float* skipb  = (const float*)d_in[7];
  const float* coutw  = (const float*)d_in[8];
  const float* cendw  = (const float*)d_in[9];
  float* out = (float*)d_out;

  // ws budget: 141.6 MB (proven ceiling >= 158.2 MB from round 1; round 2's 166.5 overflowed)
  char* p = (char*)d_ws;
  auto carve = [&](size_t bytes) { char* r = p; p += (bytes + 255) & ~(size_t)255; return r; };
  h16* w2h      = (h16*)carve((size_t)16 * 256 * 512 * 2);       //  4.19 MB
  h16* resh     = (h16*)carve((size_t)15 * 256 * 256 * 2);       //  1.97 MB
  h16* skiph    = (h16*)carve((size_t)4 * 512 * 1024 * 2);       //  4.19 MB
  h16* couth    = (h16*)carve((size_t)256 * 512 * 2);            //  0.26 MB
  h16* cendh    = (h16*)carve((size_t)256 * 256 * 2);            //  0.13 MB
  float* sbias  = (float*)carve(512 * 4);
  float* xf32   = (float*)carve((size_t)BC * TLEN * 256 * 4);    // 32.77 MB
  h16*  act     = (h16*) carve((size_t)BC * TLEN * 1024 * 2);    // 65.54 MB [b][t][(l&3)*256+c]
  h16*  sp      = (h16*) carve((size_t)BC * TLEN * 512 * 2);     // 32.77 MB
  h16* sk16 = (h16*)xf32;  // xf32 dead after dilate_15 read it (chunk-3 skip runs after)
  h16* h116 = act;         // act dead after chunk-3 skip GEMM

  prep_k<<<dim3(20994), 256, 0, stream>>>(
      dil_w, resw, skipw, coutw, cendw, skipb, w2h, resh, skiph, couth, cendh, sbias);

  for (int c0 = 0; c0 < 4; c0 += BC) {
    embed_k<<<dim3(4000, BC), 256, 0, stream>>>(tokens + (size_t)c0 * TLEN, embedw, xf32);

    for (int l = 0; l < 16; l++) {
      gemm5_k<512, 256, 512, 0><<<dim3(250, 2, BC), 256, 0, stream>>>(
          xf32, w2h + (size_t)l * 131072, dil_b + (size_t)l * 512,
          act + (l & 3) * 256, nullptr, nullptr);
      if (l < 15)
        gemm5_k<256, 1024, 256, 1><<<dim3(250, 2, BC), 256, 0, stream>>>(
            act + (l & 3) * 256, resh + (size_t)l * 65536, resb + (size_t)l * 256,
            nullptr, xf32, nullptr);
      if ((l & 3) == 3) {  // skip chunk over act layers l-3..l (before slot 0 is reused)
        const int ch = l >> 2;
        const h16* Wc = skiph + (size_t)ch * 524288;
        if (ch == 0)
          gemm5_k<1024, 1024, 1024, 2><<<dim3(250, 4, BC), 256, 0, stream>>>(
              act, Wc, sbias, sp, nullptr, nullptr);
        else if (ch < 3)
          gemm5_k<1024, 1024, 1024, 3><<<dim3(250, 4, BC), 256, 0, stream>>>(
              act, Wc, nullptr, sp, nullptr, sp);
        else
          gemm5_k<1024, 1024, 1024, 4><<<dim3(250, 4, BC), 256, 0, stream>>>(
              act, Wc, nullptr, sk16, nullptr, sp);
      }
    }

    gemm5_k<512, 512, 512, 5><<<dim3(250, 2, BC), 256, 0, stream>>>(
        sk16, couth, nullptr, h116, nullptr, nullptr);
    head_k<<<dim3(500, 1, BC), 256, 0, stream>>>(h116, cendh, out + (size_t)c0 * 256 * TLEN);
  }
}